// Round 3
// baseline (318.951 us; speedup 1.0000x reference)
//
#include <hip/hip_runtime.h>

// ---------------- fixed problem shape ----------------
#define BATCH  2
#define SEQ    2048
#define DMODEL 1024
#define NHEAD  16
#define HDIM   64
#define NROWS  (BATCH * SEQ)   // 4096
#define QKVC   (3 * DMODEL)    // 3072

typedef float f32x4 __attribute__((ext_vector_type(4)));
typedef short s16x8 __attribute__((ext_vector_type(8)));
typedef short s16x4 __attribute__((ext_vector_type(4)));

__device__ __forceinline__ unsigned short f2bf(float f) {
  unsigned int u = __float_as_uint(f);
  u = (u + 0x7FFFu + ((u >> 16) & 1u)) >> 16;   // RNE
  return (unsigned short)u;
}
__device__ __forceinline__ float bf2f(unsigned short s) {
  return __uint_as_float(((unsigned int)s) << 16);
}

// ---------------------------------------------------------------------------
// 1) row-normalize f32 weight rows (len 1024) -> bf16
// ---------------------------------------------------------------------------
__global__ __launch_bounds__(256) void k_wnorm(const float* __restrict__ W,
                                               unsigned short* __restrict__ Wh) {
  const int row = blockIdx.x, tid = threadIdx.x;
  const float4* rp = (const float4*)(W + (size_t)row * DMODEL);
  float4 v = rp[tid];
  float ss = v.x * v.x + v.y * v.y + v.z * v.z + v.w * v.w;
#pragma unroll
  for (int m = 1; m < 64; m <<= 1) ss += __shfl_xor(ss, m);
  __shared__ float part[4];
  if ((tid & 63) == 0) part[tid >> 6] = ss;
  __syncthreads();
  const float tot = part[0] + part[1] + part[2] + part[3];
  const float scale = 0.03125f / (1e-4f + sqrtf(tot) * 0.03125f);
  unsigned short* op = Wh + (size_t)row * DMODEL + tid * 4;
  op[0] = f2bf(v.x * scale); op[1] = f2bf(v.y * scale);
  op[2] = f2bf(v.z * scale); op[3] = f2bf(v.w * scale);
}

// ---------------------------------------------------------------------------
// 2) f32 -> bf16 cast
// ---------------------------------------------------------------------------
__global__ __launch_bounds__(256) void k_cast(const float* __restrict__ X,
                                              unsigned short* __restrict__ Xb) {
  const int i = blockIdx.x * 256 + threadIdx.x;
  const float4 v = ((const float4*)X)[i];
  ushort4 o = { f2bf(v.x), f2bf(v.y), f2bf(v.z), f2bf(v.w) };
  ((ushort4*)Xb)[i] = o;
}

// ---------------------------------------------------------------------------
// 3) C[M][N] = A[M][K] * B[N][K]^T  (unchanged this round)
// ---------------------------------------------------------------------------
#define LDP 88
template <int WRITE_BF16>
__global__ __launch_bounds__(256) void k_gemm_bt(const unsigned short* __restrict__ A,
                                                 const unsigned short* __restrict__ Bm,
                                                 void* __restrict__ Cv,
                                                 int M, int N, int K) {
  __shared__ unsigned short As[128 * LDP];
  __shared__ unsigned short Bs[128 * LDP];
  const int tid = threadIdx.x;
  const int nbn = N >> 7;
  const int bm = (blockIdx.x / nbn) << 7;
  const int bn = (blockIdx.x % nbn) << 7;
  const int wave = tid >> 6, lane = tid & 63;
  const int wr = (wave >> 1) << 6, wc = (wave & 1) << 6;
  const int l16 = lane & 15, lg = lane >> 4;

  f32x4 acc[4][4];
#pragma unroll
  for (int m = 0; m < 4; ++m)
#pragma unroll
    for (int n = 0; n < 4; ++n) acc[m][n] = (f32x4){0.f, 0.f, 0.f, 0.f};

  for (int k0 = 0; k0 < K; k0 += 64) {
    s16x8 ra[4], rb[4];
#pragma unroll
    for (int it = 0; it < 4; ++it) {
      const int c = it * 256 + tid;
      const int r = c >> 3, col = (c & 7) << 3;
      ra[it] = *(const s16x8*)(A + (size_t)(bm + r) * K + k0 + col);
      rb[it] = *(const s16x8*)(Bm + (size_t)(bn + r) * K + k0 + col);
    }
    __syncthreads();
#pragma unroll
    for (int it = 0; it < 4; ++it) {
      const int c = it * 256 + tid;
      const int r = c >> 3, col = (c & 7) << 3;
      *(s16x8*)(As + r * LDP + col) = ra[it];
      *(s16x8*)(Bs + r * LDP + col) = rb[it];
    }
    __syncthreads();
#pragma unroll
    for (int ks = 0; ks < 2; ++ks) {
      s16x8 af[4], bq[4];
#pragma unroll
      for (int m = 0; m < 4; ++m)
        af[m] = *(const s16x8*)(As + (wr + m * 16 + l16) * LDP + ks * 32 + lg * 8);
#pragma unroll
      for (int n = 0; n < 4; ++n)
        bq[n] = *(const s16x8*)(Bs + (wc + n * 16 + l16) * LDP + ks * 32 + lg * 8);
#pragma unroll
      for (int m = 0; m < 4; ++m)
#pragma unroll
        for (int n = 0; n < 4; ++n)
          acc[m][n] = __builtin_amdgcn_mfma_f32_16x16x32_bf16(af[m], bq[n], acc[m][n], 0, 0, 0);
    }
  }
  if (WRITE_BF16) {
    unsigned short* C = (unsigned short*)Cv;
#pragma unroll
    for (int m = 0; m < 4; ++m)
#pragma unroll
      for (int n = 0; n < 4; ++n)
#pragma unroll
        for (int r = 0; r < 4; ++r)
          C[(size_t)(bm + wr + m * 16 + lg * 4 + r) * N + (bn + wc + n * 16 + l16)] =
              f2bf(acc[m][n][r]);
  } else {
    float* C = (float*)Cv;
#pragma unroll
    for (int m = 0; m < 4; ++m)
#pragma unroll
      for (int n = 0; n < 4; ++n)
#pragma unroll
        for (int r = 0; r < 4; ++r)
          C[(size_t)(bm + wr + m * 16 + lg * 4 + r) * N + (bn + wc + n * 16 + l16)] =
              acc[m][n][r];
  }
}

// ---------------------------------------------------------------------------
// 4) normalize q,k head-vectors in-place; q rows fold attn scale AND log2(e)
//    so softmax can use raw exp2 (v_exp_f32):  0.125 * 1.44269504 = 0.18033688
// ---------------------------------------------------------------------------
__global__ __launch_bounds__(256) void k_qknorm(unsigned short* __restrict__ qkv) {
  const int row = blockIdx.x, tid = threadIdx.x;
  const int hv = tid >> 3, g = tid & 7;
  const int base = (hv < 16) ? (hv * HDIM) : (DMODEL + (hv - 16) * HDIM);
  unsigned short* p = qkv + (size_t)row * QKVC + base + g * 8;
  s16x8 v = *(const s16x8*)p;
  float f[8];
  float ss = 0.f;
#pragma unroll
  for (int j = 0; j < 8; ++j) { f[j] = bf2f((unsigned short)v[j]); ss += f[j] * f[j]; }
  ss += __shfl_xor(ss, 1); ss += __shfl_xor(ss, 2); ss += __shfl_xor(ss, 4);
  float scale = 1.f / (1e-4f + sqrtf(ss) * 0.125f);
  if (hv < 16) scale *= 0.18033688f;   // (1/sqrt(hd)) * log2(e)
  s16x8 o;
#pragma unroll
  for (int j = 0; j < 8; ++j) o[j] = (short)f2bf(f[j] * scale);
  *(s16x8*)p = o;
}

// ---------------------------------------------------------------------------
// 5) V transpose: qkv v-part -> Vt[bh][d][t]
// ---------------------------------------------------------------------------
__global__ __launch_bounds__(256) void k_vtrans(const unsigned short* __restrict__ qkv,
                                                unsigned short* __restrict__ Vt) {
  const int tt = blockIdx.x & 31, bh = blockIdx.x >> 5;
  const int b = bh >> 4, h = bh & 15;
  const int t0 = tt * 64;
  __shared__ unsigned short tile[64][80];
  const int tid = threadIdx.x;
#pragma unroll
  for (int half = 0; half < 2; ++half) {
    const int tl = half * 32 + (tid >> 3), part = tid & 7;
    s16x8 v = *(const s16x8*)(qkv + (size_t)(b * SEQ + t0 + tl) * QKVC + 2 * DMODEL +
                              h * HDIM + part * 8);
    *(s16x8*)(&tile[tl][part * 8]) = v;
  }
  __syncthreads();
#pragma unroll
  for (int half = 0; half < 2; ++half) {
    const int d = half * 32 + (tid >> 3), tp = tid & 7;
    s16x8 o;
#pragma unroll
    for (int j = 0; j < 8; ++j) o[j] = (short)tile[tp * 8 + j][d];
    *(s16x8*)(Vt + (size_t)(bh * HDIM + d) * SEQ + t0 + tp * 8) = o;
  }
}

// ---------------------------------------------------------------------------
// 6) flash attention, swapped-operand + REGISTER-PIPELINED K/V (KB=32):
//    loads for key-tile n+1 issue before compute of tile n (T14, per-wave,
//    no barriers). All buffers statically named (rule #20). exp2-domain
//    softmax (log2e folded into q).
// ---------------------------------------------------------------------------
#define PST 40
__global__ __launch_bounds__(256) void k_attn(const unsigned short* __restrict__ qkv,
                                              const unsigned short* __restrict__ Vt,
                                              unsigned short* __restrict__ O) {
  const int qt = blockIdx.x & 31, bh = blockIdx.x >> 5;
  const int b = bh >> 4, h = bh & 15;
  const int wave = threadIdx.x >> 6, lane = threadIdx.x & 63;
  const int l16 = lane & 15, lg = lane >> 4;
  const int q0 = qt * 64 + wave * 16;

  __shared__ unsigned short P[4][16 * PST];
  unsigned short* Pw = &P[wave][0];

  // Q fragments (B operand: col=q=l16, k=8*lg+j); scale*log2e pre-folded
  const size_t qbase = (size_t)(b * SEQ + q0 + l16) * QKVC + h * HDIM;
  const s16x8 aq0 = *(const s16x8*)(qkv + qbase + lg * 8);
  const s16x8 aq1 = *(const s16x8*)(qkv + qbase + 32 + lg * 8);

  // per-lane loop-invariant bases
  const unsigned short* kbase0 =
      qkv + (size_t)(b * SEQ + l16) * QKVC + DMODEL + h * HDIM + lg * 8;
  const unsigned short* vbase0 = Vt + (size_t)(bh * HDIM + l16) * SEQ + lg * 8;

  f32x4 o[4];
#pragma unroll
  for (int n = 0; n < 4; ++n) o[n] = (f32x4){0.f, 0.f, 0.f, 0.f};
  float m = -1e30f, l = 0.f;

#define LOADK(KT, K00, K01, K10, K11) {                                   \
    const unsigned short* kp = kbase0 + (size_t)(KT) * QKVC;              \
    K00 = *(const s16x8*)(kp);                                            \
    K01 = *(const s16x8*)(kp + 32);                                       \
    K10 = *(const s16x8*)(kp + 16 * QKVC);                                \
    K11 = *(const s16x8*)(kp + 16 * QKVC + 32); }

#define LOADV(KT, V0, V1, V2, V3) {                                       \
    const unsigned short* vp = vbase0 + (KT);                             \
    V0 = *(const s16x8*)(vp);                                             \
    V1 = *(const s16x8*)(vp + 16 * SEQ);                                  \
    V2 = *(const s16x8*)(vp + 32 * SEQ);                                  \
    V3 = *(const s16x8*)(vp + 48 * SEQ); }

#define COMPUTE(K00, K01, K10, K11, V0, V1, V2, V3) {                     \
    f32x4 s0 = (f32x4){0.f, 0.f, 0.f, 0.f}, s1 = s0;                     \
    __builtin_amdgcn_s_setprio(1);                                        \
    s0 = __builtin_amdgcn_mfma_f32_16x16x32_bf16(K00, aq0, s0, 0, 0, 0);  \
    s0 = __builtin_amdgcn_mfma_f32_16x16x32_bf16(K01, aq1, s0, 0, 0, 0);  \
    s1 = __builtin_amdgcn_mfma_f32_16x16x32_bf16(K10, aq0, s1, 0, 0, 0);  \
    s1 = __builtin_amdgcn_mfma_f32_16x16x32_bf16(K11, aq1, s1, 0, 0, 0);  \
    __builtin_amdgcn_s_setprio(0);                                        \
    float tm = fmaxf(fmaxf(fmaxf(s0[0], s0[1]), fmaxf(s0[2], s0[3])),     \
                     fmaxf(fmaxf(s1[0], s1[1]), fmaxf(s1[2], s1[3])));    \
    tm = fmaxf(tm, __shfl_xor(tm, 16));                                   \
    tm = fmaxf(tm, __shfl_xor(tm, 32));                                   \
    const float mnew = fmaxf(m, tm);                                      \
    const float c = exp2f(m - mnew);                                      \
    m = mnew;                                                             \
    float rs = 0.f;                                                       \
    _Pragma("unroll") for (int r = 0; r < 4; ++r) {                       \
      s0[r] = exp2f(s0[r] - mnew); rs += s0[r];                           \
      s1[r] = exp2f(s1[r] - mnew); rs += s1[r];                           \
    }                                                                     \
    rs += __shfl_xor(rs, 16);                                             \
    rs += __shfl_xor(rs, 32);                                             \
    l = l * c + rs;                                                       \
    o[0] *= c; o[1] *= c; o[2] *= c; o[3] *= c;                           \
    s16x4 p0 = { (short)f2bf(s0[0]), (short)f2bf(s0[1]),                  \
                 (short)f2bf(s0[2]), (short)f2bf(s0[3]) };                \
    s16x4 p1 = { (short)f2bf(s1[0]), (short)f2bf(s1[1]),                  \
                 (short)f2bf(s1[2]), (short)f2bf(s1[3]) };                \
    *(s16x4*)(Pw + l16 * PST + lg * 4) = p0;                              \
    *(s16x4*)(Pw + l16 * PST + 16 + lg * 4) = p1;                         \
    const s16x8 pa = *(const s16x8*)(Pw + l16 * PST + lg * 8);            \
    __builtin_amdgcn_s_setprio(1);                                        \
    o[0] = __builtin_amdgcn_mfma_f32_16x16x32_bf16(V0, pa, o[0], 0, 0, 0);\
    o[1] = __builtin_amdgcn_mfma_f32_16x16x32_bf16(V1, pa, o[1], 0, 0, 0);\
    o[2] = __builtin_amdgcn_mfma_f32_16x16x32_bf16(V2, pa, o[2], 0, 0, 0);\
    o[3] = __builtin_amdgcn_mfma_f32_16x16x32_bf16(V3, pa, o[3], 0, 0, 0);\
    __builtin_amdgcn_s_setprio(0); }

  s16x8 kA00, kA01, kA10, kA11, vA0, vA1, vA2, vA3;
  s16x8 kB00, kB01, kB10, kB11, vB0, vB1, vB2, vB3;
  LOADK(0, kA00, kA01, kA10, kA11);
  LOADV(0, vA0, vA1, vA2, vA3);
  for (int kt = 0; kt < SEQ; kt += 64) {
    LOADK(kt + 32, kB00, kB01, kB10, kB11);
    LOADV(kt + 32, vB0, vB1, vB2, vB3);
    COMPUTE(kA00, kA01, kA10, kA11, vA0, vA1, vA2, vA3);
    if (kt + 64 < SEQ) {
      LOADK(kt + 64, kA00, kA01, kA10, kA11);
      LOADV(kt + 64, vA0, vA1, vA2, vA3);
    }
    COMPUTE(kB00, kB01, kB10, kB11, vB0, vB1, vB2, vB3);
  }
#undef LOADK
#undef LOADV
#undef COMPUTE

  // epilogue: O^T[d][q] regs -> O[b][t=q][h*64+d]
  const float inv = 1.f / l;
#pragma unroll
  for (int n = 0; n < 4; ++n) {
    s16x4 ov = { (short)f2bf(o[n][0] * inv), (short)f2bf(o[n][1] * inv),
                 (short)f2bf(o[n][2] * inv), (short)f2bf(o[n][3] * inv) };
    *(s16x4*)(O + (size_t)(b * SEQ + q0 + l16) * DMODEL + h * HDIM + n * 16 + lg * 4) = ov;
  }
}

// ---------------------------------------------------------------------------
// launch: ws layout (bytes): Wq[0,6M) Wo[6M,8M) Xb[8M,16M) QKV[16M,40M) Vt[40M,48M)
// ---------------------------------------------------------------------------
extern "C" void kernel_launch(void* const* d_in, const int* in_sizes, int n_in,
                              void* d_out, int out_size, void* d_ws, size_t ws_size,
                              hipStream_t stream) {
  const float* x    = (const float*)d_in[0];
  const float* wqkv = (const float*)d_in[1];
  const float* wout = (const float*)d_in[2];
  char* ws = (char*)d_ws;
  unsigned short* Wq  = (unsigned short*)(ws);
  unsigned short* Wo  = (unsigned short*)(ws + 6291456);
  unsigned short* Xb  = (unsigned short*)(ws + 8388608);
  unsigned short* QKV = (unsigned short*)(ws + 16777216);
  unsigned short* Vt  = (unsigned short*)(ws + 41943040);
  (void)in_sizes; (void)n_in; (void)out_size; (void)ws_size;

  k_wnorm<<<QKVC, 256, 0, stream>>>(wqkv, Wq);
  k_wnorm<<<DMODEL, 256, 0, stream>>>(wout, Wo);
  k_cast<<<(NROWS * DMODEL) / 1024, 256, 0, stream>>>(x, Xb);
  k_gemm_bt<1><<<(NROWS / 128) * (QKVC / 128), 256, 0, stream>>>(
      Xb, Wq, (void*)QKV, NROWS, QKVC, DMODEL);
  k_qknorm<<<NROWS, 256, 0, stream>>>(QKV);
  k_vtrans<<<BATCH * NHEAD * (SEQ / 64), 256, 0, stream>>>(QKV, Vt);
  k_attn<<<BATCH * NHEAD * (SEQ / 64), 256, 0, stream>>>(QKV, Vt, Xb);
  k_gemm_bt<0><<<(NROWS / 128) * (DMODEL / 128), 256, 0, stream>>>(
      Xb, Wo, d_out, NROWS, DMODEL, DMODEL);
}